// Round 6
// baseline (279.557 us; speedup 1.0000x reference)
//
#include <hip/hip_runtime.h>
#include <stdint.h>

// DifferentiableSkeletonize on (2,1,256,256,256) binary fp32 mask — FUSED,
// 4-deep plane-ring software pipeline.
// dilated = avgpool3(avgpool3(x)): separable per-axis double-box [1,2,3,2,1]/9
// (zero-extended); boundary planes subtract one extra center tap; all axis
// filters + corrections commute. Pointwise tail reduces EXACTLY to
//   out = (x==0 && n>=9) ? 1 : 0      (absmax 0 confirmed R1/R3/R4/R5)
// One wave owns a (b,w) column marching h. Per h-step: 5-row load batch for
// plane h+6 (ring slot freed 4 planes ago), w-combine + d-filter (2 shfl +
// 64-bit SWAR) for plane h+2, h-SWAR + threshold, nontemporal store.

typedef float        vfloat4 __attribute__((ext_vector_type(4)));
typedef unsigned int vuint4  __attribute__((ext_vector_type(4)));

#define CH2 32
#define BLOCKS 1024    // 2 b * 8 hchunk * 64 wblocks(4 w each)

__global__ __launch_bounds__(256) void skel_fused(const float* __restrict__ x,
                                                  float* __restrict__ outp) {
    const int ln  = threadIdx.x & 63;
    const int wv  = threadIdx.x >> 6;
    const int bid = blockIdx.x;
    // XCD swizzle: XCD k (bid%8) owns a contiguous w-range of 32 -> w-halo
    // re-reads hit that XCD's L2 (verified R5: FETCH 90 MB < 134 MB input).
    const int L      = (bid & 7) * 128 + (bid >> 3);   // [0,1024)
    const int wblock = L >> 4;                         // [0,64)
    const int combo  = L & 15;
    const int b      = combo & 1;
    const int hc     = combo >> 1;                     // [0,8)
    const int w      = wblock * 4 + wv;                // [0,256)
    const int h0     = hc * CH2;
    const int hlast  = (h0 + CH2 + 1 > 255) ? 255 : (h0 + CH2 + 1);

    const vfloat4* __restrict__ xs = (const vfloat4*)x;
    vfloat4* __restrict__ os = (vfloat4*)outp;
    const uint32_t rbase = (uint32_t)b * 4194304u + (uint32_t)w * 64u + (uint32_t)ln;
    const vfloat4 vzero = {0.0f, 0.0f, 0.0f, 0.0f};

    int  co[5]; bool cv[5];
    #pragma unroll
    for (int j = 0; j < 5; ++j) {
        int wj = w + j - 2;
        cv[j]  = (wj >= 0) && (wj <= 255);
        int wc = wj < 0 ? 0 : (wj > 255 ? 255 : wj);
        co[j]  = (wc - w) * 64;
    }

    auto load5 = [&](int hp, vfloat4 R[5]) {
        int hcl = hp < 0 ? 0 : (hp > hlast ? hlast : hp);  // dup-addr -> L1 hit
        uint32_t rb = rbase + (uint32_t)hcl * 16384u;
        #pragma unroll
        for (int j = 0; j < 5; ++j) {
            vfloat4 v = xs[(int)rb + co[j]];
            R[j] = cv[j] ? v : vzero;
        }
    };

    // w-combine raw 0/1 floats, then d-filter once. Returns bytes:
    // n_dw (<=81, bits 0-6) | x-bit (bit 7).
    auto dw_from = [&](const vfloat4 R[5], int hp) -> uint32_t {
        if (hp < 0 || hp > 255) return 0u;                 // wave-uniform
        vfloat4 s = R[0] + R[4] + 2.0f * (R[1] + R[3]) + 3.0f * R[2];
        if (w == 0 || w == 255) s = s - R[2];              // w boundary corr
        uint32_t tn = (uint32_t)s.x | ((uint32_t)s.y << 8)
                    | ((uint32_t)s.z << 16) | ((uint32_t)s.w << 24);  // bytes<=9
        vuint4 u2 = __builtin_bit_cast(vuint4, R[2]);      // 1.0f -> bit29 set
        uint32_t tx = ((u2.x >> 22) & 0x80u)    | ((u2.y >> 14) & 0x8000u)
                    | ((u2.z >> 6) & 0x800000u) | ((u2.w << 2) & 0x80000000u);
        uint32_t up = (uint32_t)__shfl_up((int)tn, 1);
        uint32_t dn = (uint32_t)__shfl_down((int)tn, 1);
        if (ln == 0)  up = 0u;
        if (ln == 63) dn = 0u;
        uint64_t W = (uint64_t)(up >> 16) | ((uint64_t)tn << 16)
                   | ((uint64_t)(dn & 0xffffu) << 48);
        uint64_t S = W + ((W >> 8) << 1) + (W >> 16) * 3u + ((W >> 24) << 1) + (W >> 32);
        uint32_t n = (uint32_t)S;                          // bytes <= 81
        if (ln == 0)  n -= (tn & 0xffu);                   // d boundary corr
        if (ln == 63) n -= (tn & 0xff000000u);
        return n | tx;
    };

    auto emit = [&](int h, uint32_t a0, uint32_t a1, uint32_t a2,
                    uint32_t a3, uint32_t a4) {
        uint32_t m0 = a0 & 0x7f7f7f7fu, m1 = a1 & 0x7f7f7f7fu, m2 = a2 & 0x7f7f7f7fu,
                 m3 = a3 & 0x7f7f7f7fu, m4 = a4 & 0x7f7f7f7fu;
        uint32_t e0 = m0 & 0x00ff00ffu, e1 = m1 & 0x00ff00ffu, e2 = m2 & 0x00ff00ffu,
                 e3 = m3 & 0x00ff00ffu, e4 = m4 & 0x00ff00ffu;
        uint32_t o0 = (m0 >> 8) & 0x00ff00ffu, o1 = (m1 >> 8) & 0x00ff00ffu,
                 o2 = (m2 >> 8) & 0x00ff00ffu, o3 = (m3 >> 8) & 0x00ff00ffu,
                 o4 = (m4 >> 8) & 0x00ff00ffu;
        uint32_t ae = e0 + e4 + ((e1 + e3) << 1) + e2 * 3u;   // <=729 per 16b field
        uint32_t ao = o0 + o4 + ((o1 + o3) << 1) + o2 * 3u;
        if (h == 0 || h == 255) { ae -= e2; ao -= o2; }       // h boundary corr
        vfloat4 o;
        o.x = (((ae & 0xffffu) >= 9u) && !(a2 & 0x80u))       ? 1.0f : 0.0f;
        o.y = (((ao & 0xffffu) >= 9u) && !(a2 & 0x8000u))     ? 1.0f : 0.0f;
        o.z = (((ae >> 16) >= 9u)     && !(a2 & 0x800000u))   ? 1.0f : 0.0f;
        o.w = (((ao >> 16) >= 9u)     && !(a2 & 0x80000000u)) ? 1.0f : 0.0f;
        __builtin_nontemporal_store(o, &os[rbase + (uint32_t)h * 16384u]);
    };

    // 4-deep plane ring: slot(p) = (p - (h0-2)) & 3. Consume slot, then
    // immediately re-issue its loads for plane p+4 -> 15 loads always in
    // flight at each wait point, issue->use distance ~3 compute blocks.
    vfloat4 B0[5], B1[5], B2[5], B3[5];
    uint32_t d0, d1, d2, d3, d4, d5, d6, d7;
    load5(h0 - 2, B0); load5(h0 - 1, B1); load5(h0, B2); load5(h0 + 1, B3);
    d0 = dw_from(B0, h0 - 2); load5(h0 + 2, B0);
    d1 = dw_from(B1, h0 - 1); load5(h0 + 3, B1);
    d2 = dw_from(B2, h0    ); load5(h0 + 4, B2);
    d3 = dw_from(B3, h0 + 1); load5(h0 + 5, B3);

    for (int h = h0; h < h0 + CH2; h += 4) {
        d4 = dw_from(B0, h + 2); load5(h + 6, B0); emit(h,     d0, d1, d2, d3, d4);
        d5 = dw_from(B1, h + 3); load5(h + 7, B1); emit(h + 1, d1, d2, d3, d4, d5);
        d6 = dw_from(B2, h + 4); load5(h + 8, B2); emit(h + 2, d2, d3, d4, d5, d6);
        d7 = dw_from(B3, h + 5); load5(h + 9, B3); emit(h + 3, d3, d4, d5, d6, d7);
        d0 = d4; d1 = d5; d2 = d6; d3 = d7;
    }
}

extern "C" void kernel_launch(void* const* d_in, const int* in_sizes, int n_in,
                              void* d_out, int out_size, void* d_ws, size_t ws_size,
                              hipStream_t stream) {
    const float* x = (const float*)d_in[0];
    skel_fused<<<BLOCKS, 256, 0, stream>>>(x, (float*)d_out);
}

// Round 7
// 240.001 us; speedup vs baseline: 1.1648x; 1.1648x over previous
//
#include <hip/hip_runtime.h>
#include <stdint.h>

// DifferentiableSkeletonize on (2,1,256,256,256) binary fp32 mask — FUSED,
// LDS-cooperative staging via global_load_lds (async DMA, double-buffered).
// dilated = avgpool3(avgpool3(x)): separable per-axis double-box [1,2,3,2,1]/9
// (zero-extended); boundary planes subtract one extra center tap; all axis
// filters + corrections commute. Pointwise tail reduces EXACTLY to
//   out = (x==0 && n>=9) ? 1 : 0      (absmax 0 confirmed R1/R3-R6)
// Block = 4 waves covering w..w+3. Per h-plane: block DMAs the 8 unique
// w-halo rows (2 per wave, 1 KiB each) into LDS buf[cur^1] while computing
// plane p from buf[cur] (5x ds_read_b128 per wave, w-combine, d-filter via
// 2 shfl + 64-bit SWAR, rolling 5-plane h-window, h-SWAR, threshold, store).
// R6 lesson: compiler sinks pure register loads and collapses source-level
// pipelines (VGPR 68 < ring need 80+); global_load_lds is side-effecting and
// barrier-bounded, so the prefetch distance actually survives compilation.

typedef float        vfloat4 __attribute__((ext_vector_type(4)));
typedef unsigned int vuint4  __attribute__((ext_vector_type(4)));

#define CH2 32
#define BLOCKS 1024    // 2 b * 8 hchunk * 64 wblocks(4 w each)

__global__ __launch_bounds__(256) void skel_fused(const float* __restrict__ x,
                                                  float* __restrict__ outp) {
    __shared__ vfloat4 lds[2][8][64];   // [buf][w-slot][lane] = 16 KiB
    const int ln  = threadIdx.x & 63;
    const int wv  = threadIdx.x >> 6;
    const int bid = blockIdx.x;
    // XCD swizzle: XCD k (bid%8) owns a contiguous w-range of 32 -> halo
    // re-reads served by that XCD's L2 (R5/R6: FETCH 90-94 MB < 134 MB input).
    const int L      = (bid & 7) * 128 + (bid >> 3);   // [0,1024)
    const int wblock = L >> 4;                         // [0,64)
    const int combo  = L & 15;
    const int b      = combo & 1;
    const int hc     = combo >> 1;                     // [0,8)
    const int w0b    = wblock * 4;                     // block's first w
    const int w      = w0b + wv;
    const int h0     = hc * CH2;

    const vfloat4* __restrict__ xs = (const vfloat4*)x;
    vfloat4* __restrict__ os = (vfloat4*)outp;
    const uint32_t rbase = (uint32_t)b * 4194304u + (uint32_t)w * 64u + (uint32_t)ln;
    const vfloat4 vzero = {0.0f, 0.0f, 0.0f, 0.0f};

    // staging: wave wv owns w-slots 2wv, 2wv+1 = global rows w0b-2+slot (clamped;
    // OOB slots hold garbage and are masked at consumption via cv[]).
    const int sr0 = w0b - 2 + 2 * wv, sr1 = sr0 + 1;
    const int sc0 = sr0 < 0 ? 0 : (sr0 > 255 ? 255 : sr0);
    const int sc1 = sr1 < 0 ? 0 : (sr1 > 255 ? 255 : sr1);
    const uint32_t sb0 = (uint32_t)b * 4194304u + (uint32_t)sc0 * 64u + (uint32_t)ln;
    const uint32_t sb1 = (uint32_t)b * 4194304u + (uint32_t)sc1 * 64u + (uint32_t)ln;

    auto stage = [&](int hp, int buf) {
        int hcl = hp < 0 ? 0 : (hp > 255 ? 255 : hp);
        uint32_t off = (uint32_t)hcl * 16384u;
        __builtin_amdgcn_global_load_lds(
            (const __attribute__((address_space(1))) void*)&xs[sb0 + off],
            (__attribute__((address_space(3))) void*)&lds[buf][2 * wv][0],
            16, 0, 0);
        __builtin_amdgcn_global_load_lds(
            (const __attribute__((address_space(1))) void*)&xs[sb1 + off],
            (__attribute__((address_space(3))) void*)&lds[buf][2 * wv + 1][0],
            16, 0, 0);
    };

    bool cv[5];
    #pragma unroll
    for (int j = 0; j < 5; ++j) {
        int wj = w + j - 2;
        cv[j] = (wj >= 0) && (wj <= 255);
    }

    // w-combine + d-filter for plane hp held in lds[buf]. Returns bytes:
    // n_dw (<=81, bits 0-6) | x-bit (bit 7).
    auto dw_from = [&](int buf, int hp) -> uint32_t {
        if (hp < 0 || hp > 255) return 0u;                 // block-uniform
        vfloat4 R[5];
        #pragma unroll
        for (int j = 0; j < 5; ++j) {
            vfloat4 v = lds[buf][wv + j][ln];              // ds_read_b128
            R[j] = cv[j] ? v : vzero;
        }
        vfloat4 s = R[0] + R[4] + 2.0f * (R[1] + R[3]) + 3.0f * R[2];
        if (w == 0 || w == 255) s = s - R[2];              // w boundary corr
        uint32_t tn = (uint32_t)s.x | ((uint32_t)s.y << 8)
                    | ((uint32_t)s.z << 16) | ((uint32_t)s.w << 24);  // bytes<=9
        vuint4 u2 = __builtin_bit_cast(vuint4, R[2]);      // 1.0f -> bit29 set
        uint32_t tx = ((u2.x >> 22) & 0x80u)    | ((u2.y >> 14) & 0x8000u)
                    | ((u2.z >> 6) & 0x800000u) | ((u2.w << 2) & 0x80000000u);
        uint32_t up = (uint32_t)__shfl_up((int)tn, 1);
        uint32_t dn = (uint32_t)__shfl_down((int)tn, 1);
        if (ln == 0)  up = 0u;
        if (ln == 63) dn = 0u;
        uint64_t W = (uint64_t)(up >> 16) | ((uint64_t)tn << 16)
                   | ((uint64_t)(dn & 0xffffu) << 48);
        uint64_t S = W + ((W >> 8) << 1) + (W >> 16) * 3u + ((W >> 24) << 1) + (W >> 32);
        uint32_t n = (uint32_t)S;                          // bytes <= 81
        if (ln == 0)  n -= (tn & 0xffu);                   // d boundary corr
        if (ln == 63) n -= (tn & 0xff000000u);
        return n | tx;
    };

    auto emit = [&](int h, uint32_t a0, uint32_t a1, uint32_t a2,
                    uint32_t a3, uint32_t a4) {
        uint32_t m0 = a0 & 0x7f7f7f7fu, m1 = a1 & 0x7f7f7f7fu, m2 = a2 & 0x7f7f7f7fu,
                 m3 = a3 & 0x7f7f7f7fu, m4 = a4 & 0x7f7f7f7fu;
        uint32_t e0 = m0 & 0x00ff00ffu, e1 = m1 & 0x00ff00ffu, e2 = m2 & 0x00ff00ffu,
                 e3 = m3 & 0x00ff00ffu, e4 = m4 & 0x00ff00ffu;
        uint32_t o0 = (m0 >> 8) & 0x00ff00ffu, o1 = (m1 >> 8) & 0x00ff00ffu,
                 o2 = (m2 >> 8) & 0x00ff00ffu, o3 = (m3 >> 8) & 0x00ff00ffu,
                 o4 = (m4 >> 8) & 0x00ff00ffu;
        uint32_t ae = e0 + e4 + ((e1 + e3) << 1) + e2 * 3u;   // <=729 per field
        uint32_t ao = o0 + o4 + ((o1 + o3) << 1) + o2 * 3u;
        if (h == 0 || h == 255) { ae -= e2; ao -= o2; }       // h boundary corr
        vfloat4 o;
        o.x = (((ae & 0xffffu) >= 9u) && !(a2 & 0x80u))       ? 1.0f : 0.0f;
        o.y = (((ao & 0xffffu) >= 9u) && !(a2 & 0x8000u))     ? 1.0f : 0.0f;
        o.z = (((ae >> 16) >= 9u)     && !(a2 & 0x800000u))   ? 1.0f : 0.0f;
        o.w = (((ao >> 16) >= 9u)     && !(a2 & 0x80000000u)) ? 1.0f : 0.0f;
        __builtin_nontemporal_store(o, &os[rbase + (uint32_t)h * 16384u]);
    };

    // Protocol (invariant at loop top: buf[cur] holds plane p; stage(p+1) in
    // flight into buf[cur^1]): compute dw(p); emit(p-2); barrier (drains the
    // stage(p+1) issued last iteration -- it had a full compute phase to
    // land); stage(p+2) into the just-freed buf[cur]; swap.
    stage(h0 - 2, 0);
    __syncthreads();
    stage(h0 - 1, 1);
    uint32_t d0 = 0, d1 = 0, d2 = 0, d3 = 0;
    int cur = 0;
    const int plast = h0 + CH2 + 1;
    for (int p = h0 - 2; p <= plast; ++p) {
        uint32_t d4 = dw_from(cur, p);
        if (p >= h0 + 2) emit(p - 2, d0, d1, d2, d3, d4);
        __syncthreads();
        if (p + 2 <= plast) stage(p + 2, cur);   // block-uniform guard
        cur ^= 1;
        d0 = d1; d1 = d2; d2 = d3; d3 = d4;
    }
}

extern "C" void kernel_launch(void* const* d_in, const int* in_sizes, int n_in,
                              void* d_out, int out_size, void* d_ws, size_t ws_size,
                              hipStream_t stream) {
    const float* x = (const float*)d_in[0];
    skel_fused<<<BLOCKS, 256, 0, stream>>>(x, (float*)d_out);
}